// Round 15
// baseline (635.117 us; speedup 1.0000x reference)
//
#include <hip/hip_runtime.h>
#include <cfloat>
#include <cmath>

#define F_IN 128
#define HID 512

typedef short bf16x8 __attribute__((ext_vector_type(8)));
typedef float f32x4 __attribute__((ext_vector_type(4)));
typedef short s16x4 __attribute__((ext_vector_type(4)));

// ---- bf16 split helpers (RNE) ----
__device__ static inline void split_bf16(float v, short& hi, short& lo) {
    unsigned u = __float_as_uint(v);
    unsigned r = u + 0x7FFF + ((u >> 16) & 1);
    hi = (short)(r >> 16);
    float hf = __uint_as_float(((unsigned)(unsigned short)hi) << 16);
    float res = v - hf;
    unsigned u2 = __float_as_uint(res);
    unsigned r2 = u2 + 0x7FFF + ((u2 >> 16) & 1);
    lo = (short)(r2 >> 16);
}

__device__ static inline void gload_lds16(const void* g, void* l) {
    __builtin_amdgcn_global_load_lds(
        (const __attribute__((address_space(1))) unsigned int*)g,
        (__attribute__((address_space(3))) unsigned int*)l,
        16, 0, 0);
}

// ---------------- small utility kernels ----------------

__global__ void zero_kernel(int* __restrict__ a, int n) {
    int i = blockIdx.x * blockDim.x + threadIdx.x;
    if (i < n) a[i] = 0;
}

__global__ void count_in_kernel(const int* __restrict__ dst, int* __restrict__ cnt, int E) {
    int e = blockIdx.x * blockDim.x + threadIdx.x;
    if (e < E) atomicAdd(&cnt[dst[e]], 1);
}

// ---- multi-block scan (R13-proven: -33 us vs single-block version) ----
__global__ void scan1_kernel(const int* __restrict__ cnt, int* __restrict__ offs,
                             int* __restrict__ bsum, int n) {
    __shared__ int buf[256];
    int b = blockIdx.x, t = threadIdx.x;
    int i = b * 256 + t;
    int v = (i < n) ? cnt[i] : 0;
    buf[t] = v;
    __syncthreads();
    for (int s = 1; s < 256; s <<= 1) {
        int x = (t >= s) ? buf[t - s] : 0;
        __syncthreads();
        buf[t] += x;
        __syncthreads();
    }
    if (i < n) offs[i] = buf[t] - v;     // block-local exclusive
    if (t == 255) bsum[b] = buf[255];    // block total
}

__global__ void scan2_kernel(int* __restrict__ bsum, int nb) {
    __shared__ int buf[256];
    int t = threadIdx.x;
    int v = (t < nb) ? bsum[t] : 0;
    buf[t] = v;
    __syncthreads();
    for (int s = 1; s < 256; s <<= 1) {
        int x = (t >= s) ? buf[t - s] : 0;
        __syncthreads();
        buf[t] += x;
        __syncthreads();
    }
    if (t < nb) bsum[t] = buf[t] - v;          // exclusive over block totals
    if (t == nb - 1) bsum[nb] = buf[t];        // grand total
}

__global__ void scan3_kernel(int* __restrict__ offs, const int* __restrict__ bsum,
                             int n, int nb) {
    int i = blockIdx.x * blockDim.x + threadIdx.x;
    if (i < n) offs[i] += bsum[i >> 8];
    if (i == 0) offs[n] = bsum[nb];
}

// dis (rsqrt) + rdis (sqrt, for pool unscale) + graph-boundary starts
__global__ void dis_starts_kernel(const int* __restrict__ offs, float* __restrict__ dis,
                                  float* __restrict__ rdis,
                                  const int* __restrict__ batch, int* __restrict__ starts,
                                  int n, int G) {
    int i = blockIdx.x * blockDim.x + threadIdx.x;
    if (i >= n) return;
    float degp1 = (float)(offs[i + 1] - offs[i] + 1);  // +1 self-loop
    dis[i] = rsqrtf(degp1);
    rdis[i] = sqrtf(degp1);
    int b = batch[i];
    if (i == 0) {
        for (int g = 0; g <= b; g++) starts[g] = 0;
    } else {
        int bp = batch[i - 1];
        for (int g = bp + 1; g <= b; g++) starts[g] = i;
    }
    if (i == n - 1) {
        for (int g = b + 1; g <= G; g++) starts[g] = n;
    }
}

// countdown-cursor fill: reuses cnt (holds deg) as cursor via atomicSub
__global__ void fill_csr_kernel(const int* __restrict__ src, const int* __restrict__ dst,
                                const int* __restrict__ offs, int* __restrict__ cnt,
                                unsigned short* __restrict__ csr, int E) {
    int e = blockIdx.x * blockDim.x + threadIdx.x;
    if (e < E) {
        int d = dst[e];
        int p = atomicSub(&cnt[d], 1);  // returns old value in [1, deg]
        csr[offs[d] + p - 1] = (unsigned short)src[e];
    }
}

// all-layer W fp32 -> bf16 hi/lo planes (single launch, concatenated)
__global__ void wconv_kernel(const float* __restrict__ W1, const float* __restrict__ W2,
                             const float* __restrict__ W3, const float* __restrict__ W4,
                             short* __restrict__ Whi, short* __restrict__ Wlo) {
    int i = blockIdx.x * blockDim.x + threadIdx.x;
    const int n1 = HID * F_IN, nk = HID * HID;
    float v;
    if (i < n1) v = W1[i];
    else if (i < n1 + nk) v = W2[i - n1];
    else if (i < n1 + 2 * nk) v = W3[i - n1 - nk];
    else if (i < n1 + 3 * nk) v = W4[i - n1 - 2 * nk];
    else return;
    short h, l;
    split_bf16(v, h, l);
    Whi[i] = h;
    Wlo[i] = l;
}

// layer-1 input prescale: xs[i][c] = dis[i] * x[i][c]  (F_IN = 128)
__global__ void xscale_kernel(const float* __restrict__ x, const float* __restrict__ dis,
                              float* __restrict__ xs, int total) {
    int i = blockIdx.x * blockDim.x + threadIdx.x;
    if (i < total) xs[i] = x[i] * dis[i >> 7];
}

// -------- float4-gather aggregation, 128-col waves, zero-row padding --------
// R6-proven float4+pad-row structure. R14 change: batch width 8 -> 16 edges
// (8 dwordx4 loads in flight per lane, was 4). Avg degree = 16, so the typical
// node's ENTIRE gather completes in ONE dependent-latency round instead of two
// (the per-node cost is serial-latency-bound: offs -> csr -> shfl -> gather).
// Validity stays free: out-of-range shfl sources hold pad-row index n (zeros).
template <int F, int CHUNKS>
__global__ __launch_bounds__(256) void agg_gather4_kernel(
    const float* __restrict__ Hs, const float* __restrict__ dis,
    const int* __restrict__ offs, const unsigned short* __restrict__ csr,
    short* __restrict__ Ahi, short* __restrict__ Alo, int n) {
    constexpr int CW = 128;                  // cols per wave (32 lanes x float4)
    int blk = blockIdx.x;
    int chunk = blk & (CHUNKS - 1);
    int gt = blk / CHUNKS;
    int wave = threadIdx.x >> 6;
    int i = gt * 4 + wave;                   // this wave's node
    if (i >= n) return;                      // wave-uniform; no barriers below

    int tid = threadIdx.x & 63;
    int es = tid >> 5;                       // edge slot 0/1
    int lq = tid & 31;                       // col-quad within slice
    int colbase = chunk * CW + lq * 4;
    const float* Hbase = Hs + colbase;

    int e0 = offs[i], e1 = offs[i + 1];
    float di = dis[i];

    f32x4 acc = (f32x4){0.f, 0.f, 0.f, 0.f};
    if (es == 0) acc = *(const f32x4*)(Hbase + (size_t)i * F);   // self term

    for (int w0 = e0; w0 < e1; w0 += 64) {
        int cnt = e1 - w0; if (cnt > 64) cnt = 64;
        int idx = n;                              // pad row (zeros)
        if (tid < cnt) idx = csr[w0 + tid];       // coalesced 2B x cnt
        int nb8 = (cnt + 15) >> 4;                // batches of 16 edges (8/slot)
        for (int b = 0; b < nb8; b++) {
            int base = b * 16 + es;               // shfl src lane <= 63 always
            int j0 = __shfl(idx, base,      64);
            int j1 = __shfl(idx, base + 2,  64);
            int j2 = __shfl(idx, base + 4,  64);
            int j3 = __shfl(idx, base + 6,  64);
            int j4 = __shfl(idx, base + 8,  64);
            int j5 = __shfl(idx, base + 10, 64);
            int j6 = __shfl(idx, base + 12, 64);
            int j7 = __shfl(idx, base + 14, 64);
            f32x4 r0 = *(const f32x4*)(Hbase + (size_t)j0 * F);
            f32x4 r1 = *(const f32x4*)(Hbase + (size_t)j1 * F);
            f32x4 r2 = *(const f32x4*)(Hbase + (size_t)j2 * F);
            f32x4 r3 = *(const f32x4*)(Hbase + (size_t)j3 * F);
            f32x4 r4 = *(const f32x4*)(Hbase + (size_t)j4 * F);
            f32x4 r5 = *(const f32x4*)(Hbase + (size_t)j5 * F);
            f32x4 r6 = *(const f32x4*)(Hbase + (size_t)j6 * F);
            f32x4 r7 = *(const f32x4*)(Hbase + (size_t)j7 * F);
            #pragma unroll
            for (int q = 0; q < 4; q++) {
                acc[q] += ((r0[q] + r1[q]) + (r2[q] + r3[q]))
                        + ((r4[q] + r5[q]) + (r6[q] + r7[q]));
            }
        }
    }
    // combine the two edge slots
    acc[0] += __shfl_xor(acc[0], 32, 64);
    acc[1] += __shfl_xor(acc[1], 32, 64);
    acc[2] += __shfl_xor(acc[2], 32, 64);
    acc[3] += __shfl_xor(acc[3], 32, 64);

    if (es == 0) {
        short h[4], l[4];
        #pragma unroll
        for (int q = 0; q < 4; q++) split_bf16(acc[q] * di, h[q], l[q]);
        *(s16x4*)&Ahi[(size_t)i * F + colbase] = (s16x4){h[0], h[1], h[2], h[3]};
        *(s16x4*)&Alo[(size_t)i * F + colbase] = (s16x4){l[0], l[1], l[2], l[3]};
    }
}

// -------- split-bf16 MFMA GEMM, 128x64 tile + double-buffered prefetch --------
// R11-proven BEST (73 us): 1256 blocks + 1-deep dbuf prefetch. R12 (2-deep
// counted vmcnt) and R13 (W-in-registers) both failed to beat it -> GEMM is
// CLOSED at this structure. R13's lesson: W loads into VGPRs put an L2 round
// trip on the MFMA critical path (shared vmcnt counter); keep W in LDS.
__global__ __launch_bounds__(256) void gemm_mfma_kernel(
    const short* __restrict__ Ahi, const short* __restrict__ Alo,
    const short* __restrict__ Whi, const short* __restrict__ Wlo,
    const float* __restrict__ bias, const float* __restrict__ dis,
    float* __restrict__ Hs,
    int M, int K, int Nout, int MT, int MT8) {
    __shared__ __attribute__((aligned(16))) short lds[2][12288];  // 2 x 24 KB

    // swizzled block decode: blk = xcd + 8*(n0t + 8*mt_local); n0t fastest so
    // the A-tile stays L2-hot across its 8 N-neighbors within an XCD band.
    int blk = blockIdx.x;
    int xcd = blk & 7;
    int r = blk >> 3;
    int n0t = r & 7;
    int mt = xcd * MT8 + (r >> 3);
    if (mt >= MT) return;                 // uniform across block; no barrier reached
    int m0 = mt * 128, n0 = n0t * 64;

    int tid = threadIdx.x;
    int w = tid >> 6, l = tid & 63;
    int lrow = l & 15, lq = l >> 4;
    int w6 = w * 6;

    // per-wave staging descriptors (6 segments of 1KB each)
    const short* spl[6];
    size_t soff[6];
    int sseg[6];
    #pragma unroll
    for (int t = 0; t < 6; t++) {
        int s = w6 + t;
        const short* pl;
        int prow;
        if (s < 8)       { pl = Ahi; prow = m0 + 16 * s; }
        else if (s < 16) { pl = Alo; prow = m0 + 16 * (s - 8); }
        else if (s < 20) { pl = Whi; prow = n0 + 16 * (s - 16); }
        else             { pl = Wlo; prow = n0 + 16 * (s - 20); }
        spl[t] = pl;
        soff[t] = (size_t)(prow + lrow) * K + lq * 8;
        sseg[t] = s * 512;
    }

    f32x4 acc[4][2];
    #pragma unroll
    for (int i = 0; i < 4; i++)
        #pragma unroll
        for (int j = 0; j < 2; j++) acc[i][j] = (f32x4){0.f, 0.f, 0.f, 0.f};

    int wm = w >> 1, wn = w & 1;

    // prologue: stage K-tile 0 into buffer 0, drain, barrier
    #pragma unroll
    for (int t = 0; t < 6; t++)
        gload_lds16(spl[t] + soff[t], &lds[0][sseg[t]]);
    asm volatile("s_waitcnt vmcnt(0)" ::: "memory");
    __builtin_amdgcn_s_barrier();

    const int nt = K >> 5;
    int cur = 0;
    for (int t = 0; t < nt; t++) {
        // issue NEXT tile's loads first (latency hides under this step's work)
        if (t + 1 < nt) {
            size_t kadd = (size_t)(t + 1) * 32;
            #pragma unroll
            for (int s = 0; s < 6; s++)
                gload_lds16(spl[s] + soff[s] + kadd, &lds[cur ^ 1][sseg[s]]);
        }

        bf16x8 ah[4], al[4], wh[2], wl[2];
        #pragma unroll
        for (int i = 0; i < 4; i++) {
            ah[i] = *(const bf16x8*)&lds[cur][((wm * 4 + i) * 64 + l) * 8];
            al[i] = *(const bf16x8*)&lds[cur][((8 + wm * 4 + i) * 64 + l) * 8];
        }
        #pragma unroll
        for (int j = 0; j < 2; j++) {
            wh[j] = *(const bf16x8*)&lds[cur][((16 + wn * 2 + j) * 64 + l) * 8];
            wl[j] = *(const bf16x8*)&lds[cur][((20 + wn * 2 + j) * 64 + l) * 8];
        }
        #pragma unroll
        for (int i = 0; i < 4; i++)
            #pragma unroll
            for (int j = 0; j < 2; j++) {
                acc[i][j] = __builtin_amdgcn_mfma_f32_16x16x32_bf16(ah[i], wh[j], acc[i][j], 0, 0, 0);
                acc[i][j] = __builtin_amdgcn_mfma_f32_16x16x32_bf16(ah[i], wl[j], acc[i][j], 0, 0, 0);
                acc[i][j] = __builtin_amdgcn_mfma_f32_16x16x32_bf16(al[i], wh[j], acc[i][j], 0, 0, 0);
            }

        // end-of-step: prefetch loads done, all waves consumed buf[cur]
        asm volatile("s_waitcnt vmcnt(0)" ::: "memory");
        __builtin_amdgcn_s_barrier();
        cur ^= 1;
    }

    // hoisted per-row dis loads (16 independent, latency-hidden)
    float dv[4][4];
    #pragma unroll
    for (int i = 0; i < 4; i++) {
        int mrow = m0 + (wm * 4 + i) * 16 + lq * 4;
        #pragma unroll
        for (int rr = 0; rr < 4; rr++) {
            int mm = mrow + rr;
            dv[i][rr] = (mm < M) ? dis[mm] : 0.0f;
        }
    }

    // epilogue: C/D layout col=lane&15, row=(lane>>4)*4+reg
    #pragma unroll
    for (int j = 0; j < 2; j++) {
        int col = n0 + (wn * 2 + j) * 16 + lrow;
        float bv = bias[col];
        #pragma unroll
        for (int i = 0; i < 4; i++) {
            int mrow = m0 + (wm * 4 + i) * 16 + lq * 4;
            #pragma unroll
            for (int rr = 0; rr < 4; rr++) {
                int mm = mrow + rr;
                if (mm < M) Hs[(size_t)mm * Nout + col] = dv[i][rr] * (acc[i][j][rr] + bv);
            }
        }
    }
}

// ---------------- pooling: per-layer segment max + fraction positive ----------------
// grid (G, 8), 64 threads. Input is the dis-prescaled Hs; unscale with rdis[n].
__global__ __launch_bounds__(64) void pool_kernel(
    const float* __restrict__ Hs, const float* __restrict__ rdis,
    const int* __restrict__ starts,
    float* __restrict__ out, int layer) {
    int g = blockIdx.x;
    int c = blockIdx.y * 64 + threadIdx.x;   // 0..511
    int s = starts[g], e = starts[g + 1];
    float mx = -INFINITY;
    int pos = 0;
    #pragma unroll 4
    for (int n = s; n < e; n++) {
        float v = Hs[(size_t)n * HID + c] * rdis[n];
        mx = fmaxf(mx, v);
        pos += (v > 0.0f) ? 1 : 0;
    }
    float cntf = fmaxf((float)(e - s), 1.0f);
    out[(size_t)g * (8 * HID) + layer * HID + c] = mx;
    out[(size_t)g * (8 * HID) + 4 * HID + layer * HID + c] = (float)pos / cntf;
}

// ---------------- launcher ----------------
extern "C" void kernel_launch(void* const* d_in, const int* in_sizes, int n_in,
                              void* d_out, int out_size, void* d_ws, size_t ws_size,
                              hipStream_t stream) {
    const float* x     = (const float*)d_in[0];
    const int*   eidx  = (const int*)d_in[1];
    const int*   batch = (const int*)d_in[2];
    const float* W1 = (const float*)d_in[5];
    const float* b1 = (const float*)d_in[6];
    const float* W2 = (const float*)d_in[7];
    const float* b2 = (const float*)d_in[8];
    const float* W3 = (const float*)d_in[9];
    const float* b3 = (const float*)d_in[10];
    const float* W4 = (const float*)d_in[11];
    const float* b4 = (const float*)d_in[12];
    float* out = (float*)d_out;

    const int N = in_sizes[0] / F_IN;   // 20000
    const int E = in_sizes[1] / 2;      // 320000
    const int G = out_size / (8 * HID); // 256

    const int* src = eidx;
    const int* dst = eidx + E;

    // workspace layout (16B-aligned segments first); Hs/xs have a zero pad row N
    const size_t nW = (size_t)HID * F_IN + 3 * (size_t)HID * HID;
    char* w = (char*)d_ws;
    short* Ahi = (short*)w; w += (size_t)N * HID * sizeof(short);
    short* Alo = (short*)w; w += (size_t)N * HID * sizeof(short);
    float* Hs  = (float*)w; w += (size_t)(N + 1) * HID * sizeof(float);
    float* xs  = (float*)w; w += (size_t)(N + 1) * F_IN * sizeof(float);
    short* Whi = (short*)w; w += nW * sizeof(short);
    short* Wlo = (short*)w; w += nW * sizeof(short);
    int* offs  = (int*)w;   w += (size_t)(N + 4) * sizeof(int);
    unsigned short* csr = (unsigned short*)w; w += (size_t)E * sizeof(unsigned short);
    int* cnt   = (int*)w;   w += (size_t)N * sizeof(int);
    float* dis = (float*)w; w += (size_t)N * sizeof(float);
    float* rdis = (float*)w; w += (size_t)N * sizeof(float);
    int* starts = (int*)w;  w += (size_t)(G + 1) * sizeof(int);
    int* bsum  = (int*)w;   w += (size_t)256 * sizeof(int) + 16;

    const size_t wo1 = 0;
    const size_t wo2 = (size_t)HID * F_IN;
    const size_t wo3 = wo2 + (size_t)HID * HID;
    const size_t wo4 = wo3 + (size_t)HID * HID;

    const int TB = 256;
    const int NB = (N + 255) / 256;       // scan blocks (79)
    // ---- preprocessing: CSR over dst, dis, graph boundaries, W planes ----
    zero_kernel<<<(N + TB - 1) / TB, TB, 0, stream>>>(cnt, N);
    zero_kernel<<<(HID + TB - 1) / TB, TB, 0, stream>>>((int*)(Hs + (size_t)N * HID), HID);
    zero_kernel<<<1, TB, 0, stream>>>((int*)(xs + (size_t)N * F_IN), F_IN);
    count_in_kernel<<<(E + TB - 1) / TB, TB, 0, stream>>>(dst, cnt, E);
    scan1_kernel<<<NB, 256, 0, stream>>>(cnt, offs, bsum, N);
    scan2_kernel<<<1, 256, 0, stream>>>(bsum, NB);
    scan3_kernel<<<NB, 256, 0, stream>>>(offs, bsum, N, NB);
    dis_starts_kernel<<<(N + TB - 1) / TB, TB, 0, stream>>>(offs, dis, rdis, batch, starts, N, G);
    fill_csr_kernel<<<(E + TB - 1) / TB, TB, 0, stream>>>(src, dst, offs, cnt, csr, E);
    wconv_kernel<<<((int)nW + TB - 1) / TB, TB, 0, stream>>>(W1, W2, W3, W4, Whi, Wlo);
    xscale_kernel<<<(N * F_IN + TB - 1) / TB, TB, 0, stream>>>(x, dis, xs, N * F_IN);

    const int MT = (N + 127) / 128;        // 157 m-tiles
    const int MT8 = (MT + 7) / 8;          // per-XCD band
    const int gemm_blocks = 8 * MT8 * 8;   // 1D swizzled grid, 64-wide N-tiles
    dim3 pool_grid(G, HID / 64);

    const int NG = (N + 3) / 4;            // 4 nodes (waves) per 256-thread agg block
    const int agg1_blocks = NG * 1;        // F_IN=128: one 128-col chunk
    const int aggh_blocks = NG * 4;        // HID=512: four 128-col chunks

    // ---- layer 1: h1 = (A x) @ W1^T + b1 ----
    agg_gather4_kernel<F_IN, 1><<<agg1_blocks, 256, 0, stream>>>(xs, dis, offs, csr, Ahi, Alo, N);
    gemm_mfma_kernel<<<gemm_blocks, 256, 0, stream>>>(Ahi, Alo, Whi + wo1, Wlo + wo1, b1, dis, Hs,
                                                      N, F_IN, HID, MT, MT8);
    pool_kernel<<<pool_grid, 64, 0, stream>>>(Hs, rdis, starts, out, 0);

    // ---- layers 2..4 ----
    const size_t wos[3] = {wo2, wo3, wo4};
    const float* bs_[3] = {b2, b3, b4};
    for (int ll = 0; ll < 3; ll++) {
        agg_gather4_kernel<HID, 4><<<aggh_blocks, 256, 0, stream>>>(Hs, dis, offs, csr, Ahi, Alo, N);
        gemm_mfma_kernel<<<gemm_blocks, 256, 0, stream>>>(Ahi, Alo, Whi + wos[ll], Wlo + wos[ll], bs_[ll], dis, Hs,
                                                          N, HID, HID, MT, MT8);
        pool_kernel<<<pool_grid, 64, 0, stream>>>(Hs, rdis, starts, out, ll + 1);
    }
}

// Round 16
// 621.738 us; speedup vs baseline: 1.0215x; 1.0215x over previous
//
#include <hip/hip_runtime.h>
#include <cfloat>
#include <cmath>

#define F_IN 128
#define HID 512

typedef short bf16x8 __attribute__((ext_vector_type(8)));
typedef float f32x4 __attribute__((ext_vector_type(4)));
typedef short s16x4 __attribute__((ext_vector_type(4)));

// ---- bf16 split helpers (RNE) ----
__device__ static inline void split_bf16(float v, short& hi, short& lo) {
    unsigned u = __float_as_uint(v);
    unsigned r = u + 0x7FFF + ((u >> 16) & 1);
    hi = (short)(r >> 16);
    float hf = __uint_as_float(((unsigned)(unsigned short)hi) << 16);
    float res = v - hf;
    unsigned u2 = __float_as_uint(res);
    unsigned r2 = u2 + 0x7FFF + ((u2 >> 16) & 1);
    lo = (short)(r2 >> 16);
}

__device__ static inline void gload_lds16(const void* g, void* l) {
    __builtin_amdgcn_global_load_lds(
        (const __attribute__((address_space(1))) unsigned int*)g,
        (__attribute__((address_space(3))) unsigned int*)l,
        16, 0, 0);
}

// ---------------- small utility kernels ----------------

__global__ void zero_kernel(int* __restrict__ a, int n) {
    int i = blockIdx.x * blockDim.x + threadIdx.x;
    if (i < n) a[i] = 0;
}

__global__ void count_in_kernel(const int* __restrict__ dst, int* __restrict__ cnt, int E) {
    int e = blockIdx.x * blockDim.x + threadIdx.x;
    if (e < E) atomicAdd(&cnt[dst[e]], 1);
}

// ---- multi-block scan (R13-proven: -33 us vs single-block version) ----
__global__ void scan1_kernel(const int* __restrict__ cnt, int* __restrict__ offs,
                             int* __restrict__ bsum, int n) {
    __shared__ int buf[256];
    int b = blockIdx.x, t = threadIdx.x;
    int i = b * 256 + t;
    int v = (i < n) ? cnt[i] : 0;
    buf[t] = v;
    __syncthreads();
    for (int s = 1; s < 256; s <<= 1) {
        int x = (t >= s) ? buf[t - s] : 0;
        __syncthreads();
        buf[t] += x;
        __syncthreads();
    }
    if (i < n) offs[i] = buf[t] - v;     // block-local exclusive
    if (t == 255) bsum[b] = buf[255];    // block total
}

__global__ void scan2_kernel(int* __restrict__ bsum, int nb) {
    __shared__ int buf[256];
    int t = threadIdx.x;
    int v = (t < nb) ? bsum[t] : 0;
    buf[t] = v;
    __syncthreads();
    for (int s = 1; s < 256; s <<= 1) {
        int x = (t >= s) ? buf[t - s] : 0;
        __syncthreads();
        buf[t] += x;
        __syncthreads();
    }
    if (t < nb) bsum[t] = buf[t] - v;          // exclusive over block totals
    if (t == nb - 1) bsum[nb] = buf[t];        // grand total
}

__global__ void scan3_kernel(int* __restrict__ offs, const int* __restrict__ bsum,
                             int n, int nb) {
    int i = blockIdx.x * blockDim.x + threadIdx.x;
    if (i < n) offs[i] += bsum[i >> 8];
    if (i == 0) offs[n] = bsum[nb];
}

// dis (rsqrt) + rdis (sqrt, for pool unscale) + graph-boundary starts
__global__ void dis_starts_kernel(const int* __restrict__ offs, float* __restrict__ dis,
                                  float* __restrict__ rdis,
                                  const int* __restrict__ batch, int* __restrict__ starts,
                                  int n, int G) {
    int i = blockIdx.x * blockDim.x + threadIdx.x;
    if (i >= n) return;
    float degp1 = (float)(offs[i + 1] - offs[i] + 1);  // +1 self-loop
    dis[i] = rsqrtf(degp1);
    rdis[i] = sqrtf(degp1);
    int b = batch[i];
    if (i == 0) {
        for (int g = 0; g <= b; g++) starts[g] = 0;
    } else {
        int bp = batch[i - 1];
        for (int g = bp + 1; g <= b; g++) starts[g] = i;
    }
    if (i == n - 1) {
        for (int g = b + 1; g <= G; g++) starts[g] = n;
    }
}

// countdown-cursor fill: reuses cnt (holds deg) as cursor via atomicSub
__global__ void fill_csr_kernel(const int* __restrict__ src, const int* __restrict__ dst,
                                const int* __restrict__ offs, int* __restrict__ cnt,
                                unsigned short* __restrict__ csr, int E) {
    int e = blockIdx.x * blockDim.x + threadIdx.x;
    if (e < E) {
        int d = dst[e];
        int p = atomicSub(&cnt[d], 1);  // returns old value in [1, deg]
        csr[offs[d] + p - 1] = (unsigned short)src[e];
    }
}

// all-layer W fp32 -> bf16 hi/lo planes (single launch, concatenated)
__global__ void wconv_kernel(const float* __restrict__ W1, const float* __restrict__ W2,
                             const float* __restrict__ W3, const float* __restrict__ W4,
                             short* __restrict__ Whi, short* __restrict__ Wlo) {
    int i = blockIdx.x * blockDim.x + threadIdx.x;
    const int n1 = HID * F_IN, nk = HID * HID;
    float v;
    if (i < n1) v = W1[i];
    else if (i < n1 + nk) v = W2[i - n1];
    else if (i < n1 + 2 * nk) v = W3[i - n1 - nk];
    else if (i < n1 + 3 * nk) v = W4[i - n1 - 2 * nk];
    else return;
    short h, l;
    split_bf16(v, h, l);
    Whi[i] = h;
    Wlo[i] = l;
}

// layer-1 input prescale: xs[i][c] = dis[i] * x[i][c]  (F_IN = 128)
__global__ void xscale_kernel(const float* __restrict__ x, const float* __restrict__ dis,
                              float* __restrict__ xs, int total) {
    int i = blockIdx.x * blockDim.x + threadIdx.x;
    if (i < total) xs[i] = x[i] * dis[i >> 7];
}

// -------- float4-gather aggregation, 128-col waves, zero-row padding --------
// R6-proven float4+pad-row structure; R15 16-edge batch kept (null but harmless).
// R15 verdict: agg is L3 random-gather-throughput-bound (TLP covers latency at
// ~80% occupancy; L2-fit slices cost more instructions than they save - R5).
template <int F, int CHUNKS>
__global__ __launch_bounds__(256) void agg_gather4_kernel(
    const float* __restrict__ Hs, const float* __restrict__ dis,
    const int* __restrict__ offs, const unsigned short* __restrict__ csr,
    short* __restrict__ Ahi, short* __restrict__ Alo, int n) {
    constexpr int CW = 128;                  // cols per wave (32 lanes x float4)
    int blk = blockIdx.x;
    int chunk = blk & (CHUNKS - 1);
    int gt = blk / CHUNKS;
    int wave = threadIdx.x >> 6;
    int i = gt * 4 + wave;                   // this wave's node
    if (i >= n) return;                      // wave-uniform; no barriers below

    int tid = threadIdx.x & 63;
    int es = tid >> 5;                       // edge slot 0/1
    int lq = tid & 31;                       // col-quad within slice
    int colbase = chunk * CW + lq * 4;
    const float* Hbase = Hs + colbase;

    int e0 = offs[i], e1 = offs[i + 1];
    float di = dis[i];

    f32x4 acc = (f32x4){0.f, 0.f, 0.f, 0.f};
    if (es == 0) acc = *(const f32x4*)(Hbase + (size_t)i * F);   // self term

    for (int w0 = e0; w0 < e1; w0 += 64) {
        int cnt = e1 - w0; if (cnt > 64) cnt = 64;
        int idx = n;                              // pad row (zeros)
        if (tid < cnt) idx = csr[w0 + tid];       // coalesced 2B x cnt
        int nb8 = (cnt + 15) >> 4;                // batches of 16 edges (8/slot)
        for (int b = 0; b < nb8; b++) {
            int base = b * 16 + es;               // shfl src lane <= 63 always
            int j0 = __shfl(idx, base,      64);
            int j1 = __shfl(idx, base + 2,  64);
            int j2 = __shfl(idx, base + 4,  64);
            int j3 = __shfl(idx, base + 6,  64);
            int j4 = __shfl(idx, base + 8,  64);
            int j5 = __shfl(idx, base + 10, 64);
            int j6 = __shfl(idx, base + 12, 64);
            int j7 = __shfl(idx, base + 14, 64);
            f32x4 r0 = *(const f32x4*)(Hbase + (size_t)j0 * F);
            f32x4 r1 = *(const f32x4*)(Hbase + (size_t)j1 * F);
            f32x4 r2 = *(const f32x4*)(Hbase + (size_t)j2 * F);
            f32x4 r3 = *(const f32x4*)(Hbase + (size_t)j3 * F);
            f32x4 r4 = *(const f32x4*)(Hbase + (size_t)j4 * F);
            f32x4 r5 = *(const f32x4*)(Hbase + (size_t)j5 * F);
            f32x4 r6 = *(const f32x4*)(Hbase + (size_t)j6 * F);
            f32x4 r7 = *(const f32x4*)(Hbase + (size_t)j7 * F);
            #pragma unroll
            for (int q = 0; q < 4; q++) {
                acc[q] += ((r0[q] + r1[q]) + (r2[q] + r3[q]))
                        + ((r4[q] + r5[q]) + (r6[q] + r7[q]));
            }
        }
    }
    // combine the two edge slots
    acc[0] += __shfl_xor(acc[0], 32, 64);
    acc[1] += __shfl_xor(acc[1], 32, 64);
    acc[2] += __shfl_xor(acc[2], 32, 64);
    acc[3] += __shfl_xor(acc[3], 32, 64);

    if (es == 0) {
        short h[4], l[4];
        #pragma unroll
        for (int q = 0; q < 4; q++) split_bf16(acc[q] * di, h[q], l[q]);
        *(s16x4*)&Ahi[(size_t)i * F + colbase] = (s16x4){h[0], h[1], h[2], h[3]};
        *(s16x4*)&Alo[(size_t)i * F + colbase] = (s16x4){l[0], l[1], l[2], l[3]};
    }
}

// -------- split-bf16 MFMA GEMM, 128x64 tile + double-buffered prefetch --------
// R11-proven BEST (73 us): 1256 blocks + 1-deep dbuf prefetch. R12 (2-deep
// counted vmcnt) and R13 (W-in-registers) both failed to beat it -> GEMM is
// CLOSED at this structure. R13's lesson: W loads into VGPRs put an L2 round
// trip on the MFMA critical path (shared vmcnt counter); keep W in LDS.
__global__ __launch_bounds__(256) void gemm_mfma_kernel(
    const short* __restrict__ Ahi, const short* __restrict__ Alo,
    const short* __restrict__ Whi, const short* __restrict__ Wlo,
    const float* __restrict__ bias, const float* __restrict__ dis,
    float* __restrict__ Hs,
    int M, int K, int Nout, int MT, int MT8) {
    __shared__ __attribute__((aligned(16))) short lds[2][12288];  // 2 x 24 KB

    // swizzled block decode: blk = xcd + 8*(n0t + 8*mt_local); n0t fastest so
    // the A-tile stays L2-hot across its 8 N-neighbors within an XCD band.
    int blk = blockIdx.x;
    int xcd = blk & 7;
    int r = blk >> 3;
    int n0t = r & 7;
    int mt = xcd * MT8 + (r >> 3);
    if (mt >= MT) return;                 // uniform across block; no barrier reached
    int m0 = mt * 128, n0 = n0t * 64;

    int tid = threadIdx.x;
    int w = tid >> 6, l = tid & 63;
    int lrow = l & 15, lq = l >> 4;
    int w6 = w * 6;

    // per-wave staging descriptors (6 segments of 1KB each)
    const short* spl[6];
    size_t soff[6];
    int sseg[6];
    #pragma unroll
    for (int t = 0; t < 6; t++) {
        int s = w6 + t;
        const short* pl;
        int prow;
        if (s < 8)       { pl = Ahi; prow = m0 + 16 * s; }
        else if (s < 16) { pl = Alo; prow = m0 + 16 * (s - 8); }
        else if (s < 20) { pl = Whi; prow = n0 + 16 * (s - 16); }
        else             { pl = Wlo; prow = n0 + 16 * (s - 20); }
        spl[t] = pl;
        soff[t] = (size_t)(prow + lrow) * K + lq * 8;
        sseg[t] = s * 512;
    }

    f32x4 acc[4][2];
    #pragma unroll
    for (int i = 0; i < 4; i++)
        #pragma unroll
        for (int j = 0; j < 2; j++) acc[i][j] = (f32x4){0.f, 0.f, 0.f, 0.f};

    int wm = w >> 1, wn = w & 1;

    // prologue: stage K-tile 0 into buffer 0, drain, barrier
    #pragma unroll
    for (int t = 0; t < 6; t++)
        gload_lds16(spl[t] + soff[t], &lds[0][sseg[t]]);
    asm volatile("s_waitcnt vmcnt(0)" ::: "memory");
    __builtin_amdgcn_s_barrier();

    const int nt = K >> 5;
    int cur = 0;
    for (int t = 0; t < nt; t++) {
        // issue NEXT tile's loads first (latency hides under this step's work)
        if (t + 1 < nt) {
            size_t kadd = (size_t)(t + 1) * 32;
            #pragma unroll
            for (int s = 0; s < 6; s++)
                gload_lds16(spl[s] + soff[s] + kadd, &lds[cur ^ 1][sseg[s]]);
        }

        bf16x8 ah[4], al[4], wh[2], wl[2];
        #pragma unroll
        for (int i = 0; i < 4; i++) {
            ah[i] = *(const bf16x8*)&lds[cur][((wm * 4 + i) * 64 + l) * 8];
            al[i] = *(const bf16x8*)&lds[cur][((8 + wm * 4 + i) * 64 + l) * 8];
        }
        #pragma unroll
        for (int j = 0; j < 2; j++) {
            wh[j] = *(const bf16x8*)&lds[cur][((16 + wn * 2 + j) * 64 + l) * 8];
            wl[j] = *(const bf16x8*)&lds[cur][((20 + wn * 2 + j) * 64 + l) * 8];
        }
        #pragma unroll
        for (int i = 0; i < 4; i++)
            #pragma unroll
            for (int j = 0; j < 2; j++) {
                acc[i][j] = __builtin_amdgcn_mfma_f32_16x16x32_bf16(ah[i], wh[j], acc[i][j], 0, 0, 0);
                acc[i][j] = __builtin_amdgcn_mfma_f32_16x16x32_bf16(ah[i], wl[j], acc[i][j], 0, 0, 0);
                acc[i][j] = __builtin_amdgcn_mfma_f32_16x16x32_bf16(al[i], wh[j], acc[i][j], 0, 0, 0);
            }

        // end-of-step: prefetch loads done, all waves consumed buf[cur]
        asm volatile("s_waitcnt vmcnt(0)" ::: "memory");
        __builtin_amdgcn_s_barrier();
        cur ^= 1;
    }

    // hoisted per-row dis loads (16 independent, latency-hidden)
    float dv[4][4];
    #pragma unroll
    for (int i = 0; i < 4; i++) {
        int mrow = m0 + (wm * 4 + i) * 16 + lq * 4;
        #pragma unroll
        for (int rr = 0; rr < 4; rr++) {
            int mm = mrow + rr;
            dv[i][rr] = (mm < M) ? dis[mm] : 0.0f;
        }
    }

    // epilogue: C/D layout col=lane&15, row=(lane>>4)*4+reg
    #pragma unroll
    for (int j = 0; j < 2; j++) {
        int col = n0 + (wn * 2 + j) * 16 + lrow;
        float bv = bias[col];
        #pragma unroll
        for (int i = 0; i < 4; i++) {
            int mrow = m0 + (wm * 4 + i) * 16 + lq * 4;
            #pragma unroll
            for (int rr = 0; rr < 4; rr++) {
                int mm = mrow + rr;
                if (mm < M) Hs[(size_t)mm * Nout + col] = dv[i][rr] * (acc[i][j][rr] + bv);
            }
        }
    }
}

// ---------------- pooling: per-layer segment max + fraction positive ----------------
// R15 change: 2 waves per block (128 thr), wave w takes rows s+w, s+w+2, ...
// -> halves the serial per-wave row walk (the pool is serial-depth-bound: one
// wave walking avg-78 rows). 512 B LDS combine; empty-segment semantics
// preserved (wave-1 publishes -inf/0, combine unconditional).
__global__ __launch_bounds__(128) void pool_kernel(
    const float* __restrict__ Hs, const float* __restrict__ rdis,
    const int* __restrict__ starts,
    float* __restrict__ out, int layer) {
    __shared__ float smx[64];
    __shared__ int spos[64];
    int g = blockIdx.x;
    int wv = threadIdx.x >> 6;               // 0 or 1
    int lane = threadIdx.x & 63;
    int c = blockIdx.y * 64 + lane;          // 0..511
    int s = starts[g], e = starts[g + 1];
    float mx = -INFINITY;
    int pos = 0;
    #pragma unroll 4
    for (int n = s + wv; n < e; n += 2) {
        float v = Hs[(size_t)n * HID + c] * rdis[n];
        mx = fmaxf(mx, v);
        pos += (v > 0.0f) ? 1 : 0;
    }
    if (wv == 1) { smx[lane] = mx; spos[lane] = pos; }
    __syncthreads();
    if (wv == 0) {
        mx = fmaxf(mx, smx[lane]);
        pos += spos[lane];
        float cntf = fmaxf((float)(e - s), 1.0f);
        out[(size_t)g * (8 * HID) + layer * HID + c] = mx;
        out[(size_t)g * (8 * HID) + 4 * HID + layer * HID + c] = (float)pos / cntf;
    }
}

// ---------------- launcher ----------------
extern "C" void kernel_launch(void* const* d_in, const int* in_sizes, int n_in,
                              void* d_out, int out_size, void* d_ws, size_t ws_size,
                              hipStream_t stream) {
    const float* x     = (const float*)d_in[0];
    const int*   eidx  = (const int*)d_in[1];
    const int*   batch = (const int*)d_in[2];
    const float* W1 = (const float*)d_in[5];
    const float* b1 = (const float*)d_in[6];
    const float* W2 = (const float*)d_in[7];
    const float* b2 = (const float*)d_in[8];
    const float* W3 = (const float*)d_in[9];
    const float* b3 = (const float*)d_in[10];
    const float* W4 = (const float*)d_in[11];
    const float* b4 = (const float*)d_in[12];
    float* out = (float*)d_out;

    const int N = in_sizes[0] / F_IN;   // 20000
    const int E = in_sizes[1] / 2;      // 320000
    const int G = out_size / (8 * HID); // 256

    const int* src = eidx;
    const int* dst = eidx + E;

    // workspace layout (16B-aligned segments first); Hs/xs have a zero pad row N
    const size_t nW = (size_t)HID * F_IN + 3 * (size_t)HID * HID;
    char* w = (char*)d_ws;
    short* Ahi = (short*)w; w += (size_t)N * HID * sizeof(short);
    short* Alo = (short*)w; w += (size_t)N * HID * sizeof(short);
    float* Hs  = (float*)w; w += (size_t)(N + 1) * HID * sizeof(float);
    float* xs  = (float*)w; w += (size_t)(N + 1) * F_IN * sizeof(float);
    short* Whi = (short*)w; w += nW * sizeof(short);
    short* Wlo = (short*)w; w += nW * sizeof(short);
    int* offs  = (int*)w;   w += (size_t)(N + 4) * sizeof(int);
    unsigned short* csr = (unsigned short*)w; w += (size_t)E * sizeof(unsigned short);
    int* cnt   = (int*)w;   w += (size_t)N * sizeof(int);
    float* dis = (float*)w; w += (size_t)N * sizeof(float);
    float* rdis = (float*)w; w += (size_t)N * sizeof(float);
    int* starts = (int*)w;  w += (size_t)(G + 1) * sizeof(int);
    int* bsum  = (int*)w;   w += (size_t)256 * sizeof(int) + 16;

    const size_t wo1 = 0;
    const size_t wo2 = (size_t)HID * F_IN;
    const size_t wo3 = wo2 + (size_t)HID * HID;
    const size_t wo4 = wo3 + (size_t)HID * HID;

    const int TB = 256;
    const int NB = (N + 255) / 256;       // scan blocks (79)
    // ---- preprocessing: CSR over dst, dis, graph boundaries, W planes ----
    zero_kernel<<<(N + TB - 1) / TB, TB, 0, stream>>>(cnt, N);
    zero_kernel<<<(HID + TB - 1) / TB, TB, 0, stream>>>((int*)(Hs + (size_t)N * HID), HID);
    zero_kernel<<<1, TB, 0, stream>>>((int*)(xs + (size_t)N * F_IN), F_IN);
    count_in_kernel<<<(E + TB - 1) / TB, TB, 0, stream>>>(dst, cnt, E);
    scan1_kernel<<<NB, 256, 0, stream>>>(cnt, offs, bsum, N);
    scan2_kernel<<<1, 256, 0, stream>>>(bsum, NB);
    scan3_kernel<<<NB, 256, 0, stream>>>(offs, bsum, N, NB);
    dis_starts_kernel<<<(N + TB - 1) / TB, TB, 0, stream>>>(offs, dis, rdis, batch, starts, N, G);
    fill_csr_kernel<<<(E + TB - 1) / TB, TB, 0, stream>>>(src, dst, offs, cnt, csr, E);
    wconv_kernel<<<((int)nW + TB - 1) / TB, TB, 0, stream>>>(W1, W2, W3, W4, Whi, Wlo);
    xscale_kernel<<<(N * F_IN + TB - 1) / TB, TB, 0, stream>>>(x, dis, xs, N * F_IN);

    const int MT = (N + 127) / 128;        // 157 m-tiles
    const int MT8 = (MT + 7) / 8;          // per-XCD band
    const int gemm_blocks = 8 * MT8 * 8;   // 1D swizzled grid, 64-wide N-tiles
    dim3 pool_grid(G, HID / 64);

    const int NG = (N + 3) / 4;            // 4 nodes (waves) per 256-thread agg block
    const int agg1_blocks = NG * 1;        // F_IN=128: one 128-col chunk
    const int aggh_blocks = NG * 4;        // HID=512: four 128-col chunks

    // ---- layer 1: h1 = (A x) @ W1^T + b1 ----
    agg_gather4_kernel<F_IN, 1><<<agg1_blocks, 256, 0, stream>>>(xs, dis, offs, csr, Ahi, Alo, N);
    gemm_mfma_kernel<<<gemm_blocks, 256, 0, stream>>>(Ahi, Alo, Whi + wo1, Wlo + wo1, b1, dis, Hs,
                                                      N, F_IN, HID, MT, MT8);
    pool_kernel<<<pool_grid, 128, 0, stream>>>(Hs, rdis, starts, out, 0);

    // ---- layers 2..4 ----
    const size_t wos[3] = {wo2, wo3, wo4};
    const float* bs_[3] = {b2, b3, b4};
    for (int ll = 0; ll < 3; ll++) {
        agg_gather4_kernel<HID, 4><<<aggh_blocks, 256, 0, stream>>>(Hs, dis, offs, csr, Ahi, Alo, N);
        gemm_mfma_kernel<<<gemm_blocks, 256, 0, stream>>>(Ahi, Alo, Whi + wos[ll], Wlo + wos[ll], bs_[ll], dis, Hs,
                                                          N, HID, HID, MT, MT8);
        pool_kernel<<<pool_grid, 128, 0, stream>>>(Hs, rdis, starts, out, ll + 1);
    }
}

// Round 17
// 621.043 us; speedup vs baseline: 1.0227x; 1.0011x over previous
//
#include <hip/hip_runtime.h>
#include <cfloat>
#include <cmath>

#define F_IN 128
#define HID 512

typedef short bf16x8 __attribute__((ext_vector_type(8)));
typedef float f32x4 __attribute__((ext_vector_type(4)));
typedef short s16x4 __attribute__((ext_vector_type(4)));

// ---- bf16 split helpers (RNE) ----
__device__ static inline void split_bf16(float v, short& hi, short& lo) {
    unsigned u = __float_as_uint(v);
    unsigned r = u + 0x7FFF + ((u >> 16) & 1);
    hi = (short)(r >> 16);
    float hf = __uint_as_float(((unsigned)(unsigned short)hi) << 16);
    float res = v - hf;
    unsigned u2 = __float_as_uint(res);
    unsigned r2 = u2 + 0x7FFF + ((u2 >> 16) & 1);
    lo = (short)(r2 >> 16);
}

__device__ static inline void gload_lds16(const void* g, void* l) {
    __builtin_amdgcn_global_load_lds(
        (const __attribute__((address_space(1))) unsigned int*)g,
        (__attribute__((address_space(3))) unsigned int*)l,
        16, 0, 0);
}

// ---------------- small utility kernels ----------------

__global__ void zero_kernel(int* __restrict__ a, int n) {
    int i = blockIdx.x * blockDim.x + threadIdx.x;
    if (i < n) a[i] = 0;
}

__global__ void count_in_kernel(const int* __restrict__ dst, int* __restrict__ cnt, int E) {
    int e = blockIdx.x * blockDim.x + threadIdx.x;
    if (e < E) atomicAdd(&cnt[dst[e]], 1);
}

// ---- multi-block scan (R13-proven: -33 us vs single-block version) ----
__global__ void scan1_kernel(const int* __restrict__ cnt, int* __restrict__ offs,
                             int* __restrict__ bsum, int n) {
    __shared__ int buf[256];
    int b = blockIdx.x, t = threadIdx.x;
    int i = b * 256 + t;
    int v = (i < n) ? cnt[i] : 0;
    buf[t] = v;
    __syncthreads();
    for (int s = 1; s < 256; s <<= 1) {
        int x = (t >= s) ? buf[t - s] : 0;
        __syncthreads();
        buf[t] += x;
        __syncthreads();
    }
    if (i < n) offs[i] = buf[t] - v;     // block-local exclusive
    if (t == 255) bsum[b] = buf[255];    // block total
}

__global__ void scan2_kernel(int* __restrict__ bsum, int nb) {
    __shared__ int buf[256];
    int t = threadIdx.x;
    int v = (t < nb) ? bsum[t] : 0;
    buf[t] = v;
    __syncthreads();
    for (int s = 1; s < 256; s <<= 1) {
        int x = (t >= s) ? buf[t - s] : 0;
        __syncthreads();
        buf[t] += x;
        __syncthreads();
    }
    if (t < nb) bsum[t] = buf[t] - v;          // exclusive over block totals
    if (t == nb - 1) bsum[nb] = buf[t];        // grand total
}

__global__ void scan3_kernel(int* __restrict__ offs, const int* __restrict__ bsum,
                             int n, int nb) {
    int i = blockIdx.x * blockDim.x + threadIdx.x;
    if (i < n) offs[i] += bsum[i >> 8];
    if (i == 0) offs[n] = bsum[nb];
}

// dis (rsqrt) + rdis (sqrt, for pool unscale) + graph-boundary starts
__global__ void dis_starts_kernel(const int* __restrict__ offs, float* __restrict__ dis,
                                  float* __restrict__ rdis,
                                  const int* __restrict__ batch, int* __restrict__ starts,
                                  int n, int G) {
    int i = blockIdx.x * blockDim.x + threadIdx.x;
    if (i >= n) return;
    float degp1 = (float)(offs[i + 1] - offs[i] + 1);  // +1 self-loop
    dis[i] = rsqrtf(degp1);
    rdis[i] = sqrtf(degp1);
    int b = batch[i];
    if (i == 0) {
        for (int g = 0; g <= b; g++) starts[g] = 0;
    } else {
        int bp = batch[i - 1];
        for (int g = bp + 1; g <= b; g++) starts[g] = i;
    }
    if (i == n - 1) {
        for (int g = b + 1; g <= G; g++) starts[g] = n;
    }
}

// countdown-cursor fill: reuses cnt (holds deg) as cursor via atomicSub
__global__ void fill_csr_kernel(const int* __restrict__ src, const int* __restrict__ dst,
                                const int* __restrict__ offs, int* __restrict__ cnt,
                                unsigned short* __restrict__ csr, int E) {
    int e = blockIdx.x * blockDim.x + threadIdx.x;
    if (e < E) {
        int d = dst[e];
        int p = atomicSub(&cnt[d], 1);  // returns old value in [1, deg]
        csr[offs[d] + p - 1] = (unsigned short)src[e];
    }
}

// all-layer W fp32 -> bf16 hi/lo planes (single launch, concatenated)
__global__ void wconv_kernel(const float* __restrict__ W1, const float* __restrict__ W2,
                             const float* __restrict__ W3, const float* __restrict__ W4,
                             short* __restrict__ Whi, short* __restrict__ Wlo) {
    int i = blockIdx.x * blockDim.x + threadIdx.x;
    const int n1 = HID * F_IN, nk = HID * HID;
    float v;
    if (i < n1) v = W1[i];
    else if (i < n1 + nk) v = W2[i - n1];
    else if (i < n1 + 2 * nk) v = W3[i - n1 - nk];
    else if (i < n1 + 3 * nk) v = W4[i - n1 - 2 * nk];
    else return;
    short h, l;
    split_bf16(v, h, l);
    Whi[i] = h;
    Wlo[i] = l;
}

// layer-1 input prescale: xs[i][c] = dis[i] * x[i][c]  (F_IN = 128)
__global__ void xscale_kernel(const float* __restrict__ x, const float* __restrict__ dis,
                              float* __restrict__ xs, int total) {
    int i = blockIdx.x * blockDim.x + threadIdx.x;
    if (i < total) xs[i] = x[i] * dis[i >> 7];
}

// -------- float4-gather aggregation, 128-col waves, zero-row padding --------
// R6-proven float4+pad-row structure; R15 16-edge batch kept (null but harmless).
// R15 verdict: agg is L3 random-gather-throughput-bound (TLP covers latency at
// ~80% occupancy; L2-fit slices cost more instructions than they save - R5).
template <int F, int CHUNKS>
__global__ __launch_bounds__(256) void agg_gather4_kernel(
    const float* __restrict__ Hs, const float* __restrict__ dis,
    const int* __restrict__ offs, const unsigned short* __restrict__ csr,
    short* __restrict__ Ahi, short* __restrict__ Alo, int n) {
    constexpr int CW = 128;                  // cols per wave (32 lanes x float4)
    int blk = blockIdx.x;
    int chunk = blk & (CHUNKS - 1);
    int gt = blk / CHUNKS;
    int wave = threadIdx.x >> 6;
    int i = gt * 4 + wave;                   // this wave's node
    if (i >= n) return;                      // wave-uniform; no barriers below

    int tid = threadIdx.x & 63;
    int es = tid >> 5;                       // edge slot 0/1
    int lq = tid & 31;                       // col-quad within slice
    int colbase = chunk * CW + lq * 4;
    const float* Hbase = Hs + colbase;

    int e0 = offs[i], e1 = offs[i + 1];
    float di = dis[i];

    f32x4 acc = (f32x4){0.f, 0.f, 0.f, 0.f};
    if (es == 0) acc = *(const f32x4*)(Hbase + (size_t)i * F);   // self term

    for (int w0 = e0; w0 < e1; w0 += 64) {
        int cnt = e1 - w0; if (cnt > 64) cnt = 64;
        int idx = n;                              // pad row (zeros)
        if (tid < cnt) idx = csr[w0 + tid];       // coalesced 2B x cnt
        int nb8 = (cnt + 15) >> 4;                // batches of 16 edges (8/slot)
        for (int b = 0; b < nb8; b++) {
            int base = b * 16 + es;               // shfl src lane <= 63 always
            int j0 = __shfl(idx, base,      64);
            int j1 = __shfl(idx, base + 2,  64);
            int j2 = __shfl(idx, base + 4,  64);
            int j3 = __shfl(idx, base + 6,  64);
            int j4 = __shfl(idx, base + 8,  64);
            int j5 = __shfl(idx, base + 10, 64);
            int j6 = __shfl(idx, base + 12, 64);
            int j7 = __shfl(idx, base + 14, 64);
            f32x4 r0 = *(const f32x4*)(Hbase + (size_t)j0 * F);
            f32x4 r1 = *(const f32x4*)(Hbase + (size_t)j1 * F);
            f32x4 r2 = *(const f32x4*)(Hbase + (size_t)j2 * F);
            f32x4 r3 = *(const f32x4*)(Hbase + (size_t)j3 * F);
            f32x4 r4 = *(const f32x4*)(Hbase + (size_t)j4 * F);
            f32x4 r5 = *(const f32x4*)(Hbase + (size_t)j5 * F);
            f32x4 r6 = *(const f32x4*)(Hbase + (size_t)j6 * F);
            f32x4 r7 = *(const f32x4*)(Hbase + (size_t)j7 * F);
            #pragma unroll
            for (int q = 0; q < 4; q++) {
                acc[q] += ((r0[q] + r1[q]) + (r2[q] + r3[q]))
                        + ((r4[q] + r5[q]) + (r6[q] + r7[q]));
            }
        }
    }
    // combine the two edge slots
    acc[0] += __shfl_xor(acc[0], 32, 64);
    acc[1] += __shfl_xor(acc[1], 32, 64);
    acc[2] += __shfl_xor(acc[2], 32, 64);
    acc[3] += __shfl_xor(acc[3], 32, 64);

    if (es == 0) {
        short h[4], l[4];
        #pragma unroll
        for (int q = 0; q < 4; q++) split_bf16(acc[q] * di, h[q], l[q]);
        *(s16x4*)&Ahi[(size_t)i * F + colbase] = (s16x4){h[0], h[1], h[2], h[3]};
        *(s16x4*)&Alo[(size_t)i * F + colbase] = (s16x4){l[0], l[1], l[2], l[3]};
    }
}

// -------- split-bf16 MFMA GEMM, 128x64 tile + double-buffered prefetch --------
// R11-proven BEST (73 us): 1256 blocks + 1-deep dbuf prefetch. R12 (2-deep
// counted vmcnt) and R13 (W-in-registers) both failed to beat it -> GEMM is
// CLOSED at this structure. R13's lesson: W loads into VGPRs put an L2 round
// trip on the MFMA critical path (shared vmcnt counter); keep W in LDS.
__global__ __launch_bounds__(256) void gemm_mfma_kernel(
    const short* __restrict__ Ahi, const short* __restrict__ Alo,
    const short* __restrict__ Whi, const short* __restrict__ Wlo,
    const float* __restrict__ bias, const float* __restrict__ dis,
    float* __restrict__ Hs,
    int M, int K, int Nout, int MT, int MT8) {
    __shared__ __attribute__((aligned(16))) short lds[2][12288];  // 2 x 24 KB

    // swizzled block decode: blk = xcd + 8*(n0t + 8*mt_local); n0t fastest so
    // the A-tile stays L2-hot across its 8 N-neighbors within an XCD band.
    int blk = blockIdx.x;
    int xcd = blk & 7;
    int r = blk >> 3;
    int n0t = r & 7;
    int mt = xcd * MT8 + (r >> 3);
    if (mt >= MT) return;                 // uniform across block; no barrier reached
    int m0 = mt * 128, n0 = n0t * 64;

    int tid = threadIdx.x;
    int w = tid >> 6, l = tid & 63;
    int lrow = l & 15, lq = l >> 4;
    int w6 = w * 6;

    // per-wave staging descriptors (6 segments of 1KB each)
    const short* spl[6];
    size_t soff[6];
    int sseg[6];
    #pragma unroll
    for (int t = 0; t < 6; t++) {
        int s = w6 + t;
        const short* pl;
        int prow;
        if (s < 8)       { pl = Ahi; prow = m0 + 16 * s; }
        else if (s < 16) { pl = Alo; prow = m0 + 16 * (s - 8); }
        else if (s < 20) { pl = Whi; prow = n0 + 16 * (s - 16); }
        else             { pl = Wlo; prow = n0 + 16 * (s - 20); }
        spl[t] = pl;
        soff[t] = (size_t)(prow + lrow) * K + lq * 8;
        sseg[t] = s * 512;
    }

    f32x4 acc[4][2];
    #pragma unroll
    for (int i = 0; i < 4; i++)
        #pragma unroll
        for (int j = 0; j < 2; j++) acc[i][j] = (f32x4){0.f, 0.f, 0.f, 0.f};

    int wm = w >> 1, wn = w & 1;

    // prologue: stage K-tile 0 into buffer 0, drain, barrier
    #pragma unroll
    for (int t = 0; t < 6; t++)
        gload_lds16(spl[t] + soff[t], &lds[0][sseg[t]]);
    asm volatile("s_waitcnt vmcnt(0)" ::: "memory");
    __builtin_amdgcn_s_barrier();

    const int nt = K >> 5;
    int cur = 0;
    for (int t = 0; t < nt; t++) {
        // issue NEXT tile's loads first (latency hides under this step's work)
        if (t + 1 < nt) {
            size_t kadd = (size_t)(t + 1) * 32;
            #pragma unroll
            for (int s = 0; s < 6; s++)
                gload_lds16(spl[s] + soff[s] + kadd, &lds[cur ^ 1][sseg[s]]);
        }

        bf16x8 ah[4], al[4], wh[2], wl[2];
        #pragma unroll
        for (int i = 0; i < 4; i++) {
            ah[i] = *(const bf16x8*)&lds[cur][((wm * 4 + i) * 64 + l) * 8];
            al[i] = *(const bf16x8*)&lds[cur][((8 + wm * 4 + i) * 64 + l) * 8];
        }
        #pragma unroll
        for (int j = 0; j < 2; j++) {
            wh[j] = *(const bf16x8*)&lds[cur][((16 + wn * 2 + j) * 64 + l) * 8];
            wl[j] = *(const bf16x8*)&lds[cur][((20 + wn * 2 + j) * 64 + l) * 8];
        }
        #pragma unroll
        for (int i = 0; i < 4; i++)
            #pragma unroll
            for (int j = 0; j < 2; j++) {
                acc[i][j] = __builtin_amdgcn_mfma_f32_16x16x32_bf16(ah[i], wh[j], acc[i][j], 0, 0, 0);
                acc[i][j] = __builtin_amdgcn_mfma_f32_16x16x32_bf16(ah[i], wl[j], acc[i][j], 0, 0, 0);
                acc[i][j] = __builtin_amdgcn_mfma_f32_16x16x32_bf16(al[i], wh[j], acc[i][j], 0, 0, 0);
            }

        // end-of-step: prefetch loads done, all waves consumed buf[cur]
        asm volatile("s_waitcnt vmcnt(0)" ::: "memory");
        __builtin_amdgcn_s_barrier();
        cur ^= 1;
    }

    // hoisted per-row dis loads (16 independent, latency-hidden)
    float dv[4][4];
    #pragma unroll
    for (int i = 0; i < 4; i++) {
        int mrow = m0 + (wm * 4 + i) * 16 + lq * 4;
        #pragma unroll
        for (int rr = 0; rr < 4; rr++) {
            int mm = mrow + rr;
            dv[i][rr] = (mm < M) ? dis[mm] : 0.0f;
        }
    }

    // epilogue: C/D layout col=lane&15, row=(lane>>4)*4+reg
    #pragma unroll
    for (int j = 0; j < 2; j++) {
        int col = n0 + (wn * 2 + j) * 16 + lrow;
        float bv = bias[col];
        #pragma unroll
        for (int i = 0; i < 4; i++) {
            int mrow = m0 + (wm * 4 + i) * 16 + lq * 4;
            #pragma unroll
            for (int rr = 0; rr < 4; rr++) {
                int mm = mrow + rr;
                if (mm < M) Hs[(size_t)mm * Nout + col] = dv[i][rr] * (acc[i][j][rr] + bv);
            }
        }
    }
}

// ---------------- pooling: per-layer segment max + fraction positive ----------------
// R16 change: 4 waves per block (256 thr), wave w takes rows s+w, s+w+4, ...
// (R15's 2-wave split measured -13 us as predicted; same mechanism, ~20 serial
// iterations/wave now). Waves 1-3 publish to LDS, wave 0 combines.
// Empty-segment semantics preserved (-inf/0 published, combine unconditional).
__global__ __launch_bounds__(256) void pool_kernel(
    const float* __restrict__ Hs, const float* __restrict__ rdis,
    const int* __restrict__ starts,
    float* __restrict__ out, int layer) {
    __shared__ float smx[3][64];
    __shared__ int spos[3][64];
    int g = blockIdx.x;
    int wv = threadIdx.x >> 6;               // 0..3
    int lane = threadIdx.x & 63;
    int c = blockIdx.y * 64 + lane;          // 0..511
    int s = starts[g], e = starts[g + 1];
    float mx = -INFINITY;
    int pos = 0;
    #pragma unroll 2
    for (int n = s + wv; n < e; n += 4) {
        float v = Hs[(size_t)n * HID + c] * rdis[n];
        mx = fmaxf(mx, v);
        pos += (v > 0.0f) ? 1 : 0;
    }
    if (wv != 0) { smx[wv - 1][lane] = mx; spos[wv - 1][lane] = pos; }
    __syncthreads();
    if (wv == 0) {
        mx = fmaxf(fmaxf(mx, smx[0][lane]), fmaxf(smx[1][lane], smx[2][lane]));
        pos += spos[0][lane] + spos[1][lane] + spos[2][lane];
        float cntf = fmaxf((float)(e - s), 1.0f);
        out[(size_t)g * (8 * HID) + layer * HID + c] = mx;
        out[(size_t)g * (8 * HID) + 4 * HID + layer * HID + c] = (float)pos / cntf;
    }
}

// ---------------- launcher ----------------
extern "C" void kernel_launch(void* const* d_in, const int* in_sizes, int n_in,
                              void* d_out, int out_size, void* d_ws, size_t ws_size,
                              hipStream_t stream) {
    const float* x     = (const float*)d_in[0];
    const int*   eidx  = (const int*)d_in[1];
    const int*   batch = (const int*)d_in[2];
    const float* W1 = (const float*)d_in[5];
    const float* b1 = (const float*)d_in[6];
    const float* W2 = (const float*)d_in[7];
    const float* b2 = (const float*)d_in[8];
    const float* W3 = (const float*)d_in[9];
    const float* b3 = (const float*)d_in[10];
    const float* W4 = (const float*)d_in[11];
    const float* b4 = (const float*)d_in[12];
    float* out = (float*)d_out;

    const int N = in_sizes[0] / F_IN;   // 20000
    const int E = in_sizes[1] / 2;      // 320000
    const int G = out_size / (8 * HID); // 256

    const int* src = eidx;
    const int* dst = eidx + E;

    // workspace layout (16B-aligned segments first); Hs/xs have a zero pad row N
    const size_t nW = (size_t)HID * F_IN + 3 * (size_t)HID * HID;
    char* w = (char*)d_ws;
    short* Ahi = (short*)w; w += (size_t)N * HID * sizeof(short);
    short* Alo = (short*)w; w += (size_t)N * HID * sizeof(short);
    float* Hs  = (float*)w; w += (size_t)(N + 1) * HID * sizeof(float);
    float* xs  = (float*)w; w += (size_t)(N + 1) * F_IN * sizeof(float);
    short* Whi = (short*)w; w += nW * sizeof(short);
    short* Wlo = (short*)w; w += nW * sizeof(short);
    int* offs  = (int*)w;   w += (size_t)(N + 4) * sizeof(int);
    unsigned short* csr = (unsigned short*)w; w += (size_t)E * sizeof(unsigned short);
    int* cnt   = (int*)w;   w += (size_t)N * sizeof(int);
    float* dis = (float*)w; w += (size_t)N * sizeof(float);
    float* rdis = (float*)w; w += (size_t)N * sizeof(float);
    int* starts = (int*)w;  w += (size_t)(G + 1) * sizeof(int);
    int* bsum  = (int*)w;   w += (size_t)256 * sizeof(int) + 16;

    const size_t wo1 = 0;
    const size_t wo2 = (size_t)HID * F_IN;
    const size_t wo3 = wo2 + (size_t)HID * HID;
    const size_t wo4 = wo3 + (size_t)HID * HID;

    const int TB = 256;
    const int NB = (N + 255) / 256;       // scan blocks (79)
    // ---- preprocessing: CSR over dst, dis, graph boundaries, W planes ----
    zero_kernel<<<(N + TB - 1) / TB, TB, 0, stream>>>(cnt, N);
    zero_kernel<<<(HID + TB - 1) / TB, TB, 0, stream>>>((int*)(Hs + (size_t)N * HID), HID);
    zero_kernel<<<1, TB, 0, stream>>>((int*)(xs + (size_t)N * F_IN), F_IN);
    count_in_kernel<<<(E + TB - 1) / TB, TB, 0, stream>>>(dst, cnt, E);
    scan1_kernel<<<NB, 256, 0, stream>>>(cnt, offs, bsum, N);
    scan2_kernel<<<1, 256, 0, stream>>>(bsum, NB);
    scan3_kernel<<<NB, 256, 0, stream>>>(offs, bsum, N, NB);
    dis_starts_kernel<<<(N + TB - 1) / TB, TB, 0, stream>>>(offs, dis, rdis, batch, starts, N, G);
    fill_csr_kernel<<<(E + TB - 1) / TB, TB, 0, stream>>>(src, dst, offs, cnt, csr, E);
    wconv_kernel<<<((int)nW + TB - 1) / TB, TB, 0, stream>>>(W1, W2, W3, W4, Whi, Wlo);
    xscale_kernel<<<(N * F_IN + TB - 1) / TB, TB, 0, stream>>>(x, dis, xs, N * F_IN);

    const int MT = (N + 127) / 128;        // 157 m-tiles
    const int MT8 = (MT + 7) / 8;          // per-XCD band
    const int gemm_blocks = 8 * MT8 * 8;   // 1D swizzled grid, 64-wide N-tiles
    dim3 pool_grid(G, HID / 64);

    const int NG = (N + 3) / 4;            // 4 nodes (waves) per 256-thread agg block
    const int agg1_blocks = NG * 1;        // F_IN=128: one 128-col chunk
    const int aggh_blocks = NG * 4;        // HID=512: four 128-col chunks

    // ---- layer 1: h1 = (A x) @ W1^T + b1 ----
    agg_gather4_kernel<F_IN, 1><<<agg1_blocks, 256, 0, stream>>>(xs, dis, offs, csr, Ahi, Alo, N);
    gemm_mfma_kernel<<<gemm_blocks, 256, 0, stream>>>(Ahi, Alo, Whi + wo1, Wlo + wo1, b1, dis, Hs,
                                                      N, F_IN, HID, MT, MT8);
    pool_kernel<<<pool_grid, 256, 0, stream>>>(Hs, rdis, starts, out, 0);

    // ---- layers 2..4 ----
    const size_t wos[3] = {wo2, wo3, wo4};
    const float* bs_[3] = {b2, b3, b4};
    for (int ll = 0; ll < 3; ll++) {
        agg_gather4_kernel<HID, 4><<<aggh_blocks, 256, 0, stream>>>(Hs, dis, offs, csr, Ahi, Alo, N);
        gemm_mfma_kernel<<<gemm_blocks, 256, 0, stream>>>(Ahi, Alo, Whi + wos[ll], Wlo + wos[ll], bs_[ll], dis, Hs,
                                                          N, HID, HID, MT, MT8);
        pool_kernel<<<pool_grid, 256, 0, stream>>>(Hs, rdis, starts, out, ll + 1);
    }
}